// Round 9
// baseline (225.218 us; speedup 1.0000x reference)
//
#include <hip/hip_runtime.h>
#include <stdint.h>

// B=4, S=2048, d=1024. fp32 in/out, f16 MFMA internally.
// cvt(x,W) -> QKV gemm (128^2, BK=32, triple-buffer, counted vmcnt(4),
// conflict-free (row>>1) swizzle) -> transpose V (vec) -> scores gemm (same
// engine, fused col-stats) -> stats2 -> PV (64x256, XCD-quartet swizzle, dbuf).

typedef __attribute__((ext_vector_type(8))) _Float16 half8;
typedef __attribute__((ext_vector_type(4))) float f32x4;
typedef __attribute__((ext_vector_type(8))) unsigned short ushort8;

__device__ __forceinline__ ushort f2h(float f) {
  _Float16 h = (_Float16)f;
  union { _Float16 h; ushort u; } v; v.h = h; return v.u;
}

__device__ __forceinline__ void gload_lds16(const ushort* g, ushort* l) {
  __builtin_amdgcn_global_load_lds(
      (const __attribute__((address_space(1))) void*)g,
      (__attribute__((address_space(3))) void*)l, 16, 0, 0);
}

// ------------- merged convert kernel: x f32->f16, W f32->f16 transposed ------
__global__ void k_cvt_xw(const float* __restrict__ x, ushort* __restrict__ xh,
                         const float* __restrict__ Wq, const float* __restrict__ Wk,
                         const float* __restrict__ Wv, ushort* __restrict__ Wt) {
  __shared__ ushort tile[32][33];
  int bid = blockIdx.x;
  if (bid < 8192) {
    int i = (bid * 256 + threadIdx.x) * 4;
    float4 v = *(const float4*)(x + i);
    ushort4 o;
    o.x = f2h(v.x); o.y = f2h(v.y); o.z = f2h(v.z); o.w = f2h(v.w);
    *(ushort4*)(xh + i) = o;
  } else {
    int wb = bid - 8192;                 // 0..3071
    int zz = wb >> 10;                   // matrix id
    int rem = wb & 1023;
    int e0 = (rem & 31) * 32, d0 = (rem >> 5) * 32;
    const float* W = zz == 0 ? Wq : zz == 1 ? Wk : Wv;
    int tix = threadIdx.x & 31, tiy = threadIdx.x >> 5;
    for (int r = tiy; r < 32; r += 8)
      tile[r][tix] = f2h(W[(size_t)(d0 + r) * 1024 + e0 + tix]);
    __syncthreads();
    ushort* out = Wt + (size_t)zz * 1024 * 1024;
    for (int r = tiy; r < 32; r += 8)
      out[(size_t)(e0 + r) * 1024 + d0 + tix] = tile[tix][r];
  }
}

// V f16 [b*2048+j][e] -> Vt [b][e][j], vectorized 64x64 tiles
__global__ void k_tr_v(const ushort* __restrict__ V, ushort* __restrict__ Vt) {
  __shared__ ushort tile[64][72];
  int b = blockIdx.z;
  int e0 = blockIdx.x * 64, j0 = blockIdx.y * 64;
  const ushort* src = V + (size_t)b * 2097152;
  ushort* dst = Vt + (size_t)b * 2097152;
  int r = threadIdx.x >> 3, c = (threadIdx.x & 7) * 8;
#pragma unroll
  for (int h = 0; h < 2; ++h) {
    ushort8 v = *(const ushort8*)&src[(size_t)(j0 + h * 32 + r) * 1024 + e0 + c];
    *(ushort8*)&tile[h * 32 + r][c] = v;
  }
  __syncthreads();
#pragma unroll
  for (int h = 0; h < 2; ++h) {
    int er = h * 32 + r;
    ushort8 o;
#pragma unroll
    for (int q = 0; q < 8; ++q) o[q] = tile[c + q][er];
    *(ushort8*)&dst[(size_t)(e0 + er) * 2048 + j0 + c] = o;
  }
}

// ======= 128x128 GEMM engine: BK=32, triple-buffer, counted vmcnt(4) =======
// Swizzle: phys_chunk = chunk ^ ((row>>1)&3) (0-conflict). Staged via
// inverse-swizzled global source (gload dest linear); read swizzled.
// EPI 0: QKV split. EPI 1: scores + fused column (m,z) partials.
template <int EPI>
__global__ __launch_bounds__(256)
void k_gemm32(const ushort* __restrict__ A, const ushort* __restrict__ Bt,
              void* o0, void* o1, void* o2,
              float* __restrict__ pm, float* __restrict__ pz) {
  int bm, bn, bz = 0;
  if (EPI == 0) {
    int wg = blockIdx.x;                        // 1536 = 8 * 192, bijective
    int swz = (wg & 7) * 192 + (wg >> 3);
    bm = swz / 24; bn = swz % 24;
  } else {
    bm = blockIdx.y; bn = blockIdx.x; bz = blockIdx.z;
    if (bn > bm) return;                        // fully-masked causal tile
    A  += (size_t)bz * 2097152;
    Bt += (size_t)bz * 2097152;
  }
  __shared__ __align__(16) ushort As[3][128 * 32];
  __shared__ __align__(16) ushort Bs[3][128 * 32];
  __shared__ float red[4][4][16][2];

  const int t = threadIdx.x, lane = t & 63, wv = t >> 6;
  const int wm = (wv >> 1) * 64, wn = (wv & 1) * 64, l15 = lane & 15;
  const int srcc = (((t & 3) ^ ((t >> 3) & 3)) * 8);
  const ushort* ga = A + (size_t)(bm * 128 + (t >> 2)) * 1024 + srcc;
  const ushort* gb = Bt + (size_t)(bn * 128 + (t >> 2)) * 1024 + srcc;
  const int dst0 = t * 8;

  int rA[4], rB[4];
#pragma unroll
  for (int i = 0; i < 4; ++i) {
    rA[i] = (wm + i * 16 + l15) * 32;
    rB[i] = (wn + i * 16 + l15) * 32;
  }
  const int ck = (((lane >> 4) ^ ((l15 >> 1) & 3)) << 3);  // swizzled k-chunk

  f32x4 acc[4][4] = {};

#define STG(kt)                                                              \
  {                                                                          \
    ushort* la = (ushort*)As[(kt) % 3] + dst0;                               \
    ushort* lb = (ushort*)Bs[(kt) % 3] + dst0;                               \
    gload_lds16(ga + (kt) * 32, la);                                         \
    gload_lds16(ga + 65536 + (kt) * 32, la + 2048);                          \
    gload_lds16(gb + (kt) * 32, lb);                                         \
    gload_lds16(gb + 65536 + (kt) * 32, lb + 2048);                          \
  }

  STG(0);
  STG(1);
  for (int kt = 0; kt < 32; ++kt) {
    if (kt < 31) asm volatile("s_waitcnt vmcnt(4)" ::: "memory");
    else         asm volatile("s_waitcnt vmcnt(0)" ::: "memory");
    __builtin_amdgcn_s_barrier();
    __builtin_amdgcn_sched_barrier(0);
    if (kt + 2 < 32) STG(kt + 2);
    const ushort* Ab = As[kt % 3];
    const ushort* Bb = Bs[kt % 3];
    half8 af[4], bf[4];
#pragma unroll
    for (int i = 0; i < 4; ++i) {
      af[i] = *(const half8*)&Ab[rA[i] + ck];
      bf[i] = *(const half8*)&Bb[rB[i] + ck];
    }
    __builtin_amdgcn_s_setprio(1);
#pragma unroll
    for (int i = 0; i < 4; ++i)
#pragma unroll
      for (int j = 0; j < 4; ++j)
        acc[i][j] = __builtin_amdgcn_mfma_f32_16x16x32_f16(af[i], bf[j], acc[i][j], 0, 0, 0);
    __builtin_amdgcn_s_setprio(0);
  }
#undef STG

  const int row0 = bm * 128 + wm + ((lane >> 4) << 2);
  const int colb = bn * 128 + wn + l15;
  if (EPI == 0) {
    int mat = bn >> 3;
    ushort* dst = mat == 0 ? (ushort*)o0 : mat == 1 ? (ushort*)o1 : (ushort*)o2;
    int cn0 = colb & 1023;
#pragma unroll
    for (int i = 0; i < 4; ++i)
#pragma unroll
      for (int j = 0; j < 4; ++j)
#pragma unroll
        for (int r = 0; r < 4; ++r)
          dst[(size_t)(row0 + i * 16 + r) * 1024 + cn0 + j * 16] = f2h(acc[i][j][r]);
  } else {
    float* sc = (float*)o0 + (size_t)bz * 4194304;
    float fm[4] = {-1e30f, -1e30f, -1e30f, -1e30f};
    float fz[4] = {0.f, 0.f, 0.f, 0.f};
#pragma unroll
    for (int i = 0; i < 4; ++i)
#pragma unroll
      for (int j = 0; j < 4; ++j) {
        int col = colb + j * 16;
#pragma unroll
        for (int r = 0; r < 4; ++r) {
          int row = row0 + i * 16 + r;
          bool ok = col <= row;
          float w = ok ? acc[i][j][r] * 0.03125f : -1e30f;  // 1/sqrt(1024)
          sc[(size_t)row * 2048 + col] = w;
          float nm = fmaxf(fm[j], w);
          fz[j] = fz[j] * __expf(fm[j] - nm) + (ok ? __expf(w - nm) : 0.f);
          fm[j] = nm;
        }
      }
#pragma unroll
    for (int j = 0; j < 4; ++j) {
#pragma unroll
      for (int mk = 16; mk <= 32; mk <<= 1) {
        float om = __shfl_xor(fm[j], mk);
        float oz = __shfl_xor(fz[j], mk);
        float nm = fmaxf(fm[j], om);
        fz[j] = fz[j] * __expf(fm[j] - nm) + oz * __expf(om - nm);
        fm[j] = nm;
      }
    }
    if (lane < 16) {
#pragma unroll
      for (int j = 0; j < 4; ++j) {
        red[wv][j][l15][0] = fm[j];
        red[wv][j][l15][1] = fz[j];
      }
    }
    __syncthreads();
    if (t < 128) {
      int wnid = t >> 6, jj = (t >> 4) & 3, ll = t & 15;
      float m0 = red[wnid][jj][ll][0], z0 = red[wnid][jj][ll][1];
      float m1 = red[wnid + 2][jj][ll][0], z1 = red[wnid + 2][jj][ll][1];
      float nm = fmaxf(m0, m1);
      float zz = z0 * __expf(m0 - nm) + z1 * __expf(m1 - nm);
      size_t po = ((size_t)bz * 16 + bm) * 2048 + bn * 128 + wnid * 64 + jj * 16 + ll;
      pm[po] = nm;
      pz[po] = zz;
    }
  }
}

// ---- stats2: combine 16 row-tile partials per column (skip unwritten) ----
__global__ void k_stats2(const float* __restrict__ pm, const float* __restrict__ pz,
                         float* __restrict__ cm, float* __restrict__ cz) {
  int b = blockIdx.z;
  int j = blockIdx.x * 256 + threadIdx.x;
  int cmin = j >> 7;
  float m = -1e30f;
  for (int c = cmin; c < 16; ++c)
    m = fmaxf(m, pm[((size_t)b * 16 + c) * 2048 + j]);
  float zs = 0.f;
  for (int c = cmin; c < 16; ++c) {
    float zz = pz[((size_t)b * 16 + c) * 2048 + j];
    if (zz > 0.f) zs += zz * __expf(pm[((size_t)b * 16 + c) * 2048 + j] - m);
  }
  cm[(size_t)b * 2048 + j] = m;
  cz[(size_t)b * 2048 + j] = zs > 0.f ? 1.0f / zs : 0.f;
}

// ===== PV gemm: 64x256 tiles, 512 blocks, XCD-quartet swizzle, dbuf =====
// wg -> (z,bm,bn): the 4 bn-siblings of one (bm,z) land on the SAME XCD
// (wg ≡ xcd mod 8) so Sc rows are fetched once per quartet (L2 hits after);
// per-XCD Sigma(bm+1) is exactly balanced via (v, v+1) -> (bm, 31-bm) pairing.
__global__ __launch_bounds__(256, 2)
void k_pv(const float* __restrict__ Sc, const float* __restrict__ cm,
          const float* __restrict__ cz, const ushort* __restrict__ Vt,
          float* __restrict__ out) {
  const int wg = blockIdx.x;
  const int xcd = wg & 7, s = wg >> 3;    // s 0..63
  const int bn = s & 3;
  const int u = s >> 2;                   // 0..15
  const int pid = xcd * 16 + u;           // 0..127
  const int z = pid & 3;
  const int v = pid >> 2;                 // 0..31
  const int bm = (v & 1) ? 31 - (v >> 1) : (v >> 1);
  const float* S = Sc + (size_t)z * 4194304;
  const float* cmb = cm + (size_t)z * 2048;
  const float* czb = cz + (size_t)z * 2048;
  const ushort* Vb = Vt + (size_t)z * 2097152;
  float* ob = out + (size_t)z * 2097152;

  __shared__ __align__(16) ushort As[2][64 * 64];    // 16 KB
  __shared__ __align__(16) ushort Bs[2][256 * 64];   // 64 KB

  const int t = threadIdx.x, lane = t & 63, wv = t >> 6;
  const int wn = wv * 64, l15 = lane & 15;
  const int nk = bm + 1;

  const int tr = t >> 3;                       // 0..31
  const int lc = (t & 7) ^ (tr & 7);           // logical 16B chunk (swizzle inv)
  const ushort* gB = Vb + (size_t)(bn * 256 + tr) * 2048 + lc * 8;
  const float*  gS = S + (size_t)(bm * 64 + tr) * 2048 + lc * 8;

  f32x4 acc[4][4] = {};
  f32x4 a0_0, a1_0, a2_0, a3_0, m0_0, m1_0, z0_0, z1_0;
  f32x4 a0_1, a1_1, a2_1, a3_1, m0_1, m1_1, z0_1, z1_1;

#define IB(kt, buf)                                                           \
  {                                                                           \
    ushort* lb = (ushort*)Bs[buf] + t * 8;                                    \
    const ushort* src = gB + (kt) * 64;                                       \
    _Pragma("unroll") for (int g2 = 0; g2 < 8; ++g2)                          \
        gload_lds16(src + (size_t)(g2 * 32) * 2048, lb + g2 * 2048);          \
  }
#define IA(kt, A0, A1, A2, A3, M0, M1, Z0, Z1)                                \
  {                                                                           \
    const float* sp = gS + (kt) * 64;                                         \
    A0 = *(const f32x4*)sp;                                                   \
    A1 = *(const f32x4*)(sp + 4);                                             \
    A2 = *(const f32x4*)(sp + 32 * 2048);                                     \
    A3 = *(const f32x4*)(sp + 32 * 2048 + 4);                                 \
    const float* mp = cmb + (kt) * 64 + lc * 8;                               \
    const float* zp = czb + (kt) * 64 + lc * 8;                               \
    M0 = *(const f32x4*)mp; M1 = *(const f32x4*)(mp + 4);                     \
    Z0 = *(const f32x4*)zp; Z1 = *(const f32x4*)(zp + 4);                     \
  }
#define EW(buf, A0, A1, A2, A3, M0, M1, Z0, Z1)                               \
  {                                                                           \
    ushort8 p;                                                                \
    _Pragma("unroll") for (int qq = 0; qq < 4; ++qq) {                        \
      p[qq] = f2h(__expf(A0[qq] - M0[qq]) * Z0[qq]);                          \
      p[4 + qq] = f2h(__expf(A1[qq] - M1[qq]) * Z1[qq]);                      \
    }                                                                         \
    *(ushort8*)&As[buf][t * 8] = p;                                           \
    _Pragma("unroll") for (int qq = 0; qq < 4; ++qq) {                        \
      p[qq] = f2h(__expf(A2[qq] - M0[qq]) * Z0[qq]);                          \
      p[4 + qq] = f2h(__expf(A3[qq] - M1[qq]) * Z1[qq]);                      \
    }                                                                         \
    *(ushort8*)&As[buf][t * 8 + 2048] = p;                                    \
  }
#define COMP(buf)                                                             \
  {                                                                           \
    _Pragma("unroll") for (int kk = 0; kk < 2; ++kk) {                        \
      const int cpk = (((kk * 4) + (lane >> 4)) ^ (l15 & 7)) * 8;             \
      half8 af[4], bf[4];                                                     \
      _Pragma("unroll") for (int i = 0; i < 4; ++i) {                         \
        af[i] = *(const half8*)&As[buf][(i * 16 + l15) * 64 + cpk];           \
        bf[i] = *(const half8*)&Bs[buf][(wn + i * 16 + l15) * 64 + cpk];      \
      }                                                                       \
      __builtin_amdgcn_s_setprio(1);                                          \
      _Pragma("unroll") for (int i = 0; i < 4; ++i)                           \
          _Pragma("unroll") for (int j = 0; j < 4; ++j)                       \
          acc[i][j] = __builtin_amdgcn_mfma_f32_16x16x32_f16(                 \
              af[i], bf[j], acc[i][j], 0, 0, 0);                              \
      __builtin_amdgcn_s_setprio(0);                                         \
    }                                                                         \
  }
#define BODY(buf, nbuf, S2, S3)                                               \
  {                                                                           \
    if (kt + 1 < nk) asm volatile("s_waitcnt vmcnt(16)" ::: "memory");        \
    else             asm volatile("s_waitcnt vmcnt(0)" ::: "memory");         \
    __builtin_amdgcn_s_barrier();                                             \
    __builtin_amdgcn_sched_barrier(0);                                        \
    COMP(buf);                                                                \
    if (kt + 1 < nk) {                                                        \
      EW(nbuf, a0_##S2, a1_##S2, a2_##S2, a3_##S2, m0_##S2, m1_##S2,          \
         z0_##S2, z1_##S2);                                                   \
    }                                                                         \
    asm volatile("s_waitcnt lgkmcnt(0)" ::: "memory");                        \
    __builtin_amdgcn_s_barrier();                                             \
    __builtin_amdgcn_sched_barrier(0);                                        \
    if (kt + 2 < nk) {                                                        \
      IA(kt + 2, a0_##S3, a1_##S3, a2_##S3, a3_##S3, m0_##S3, m1_##S3,        \
         z0_##S3, z1_##S3);                                                   \
      IB(kt + 2, buf);                                                        \
    }                                                                         \
  }

  IA(0, a0_0, a1_0, a2_0, a3_0, m0_0, m1_0, z0_0, z1_0);
  IB(0, 0);
  EW(0, a0_0, a1_0, a2_0, a3_0, m0_0, m1_0, z0_0, z1_0);
  if (nk > 1) {
    IA(1, a0_1, a1_1, a2_1, a3_1, m0_1, m1_1, z0_1, z1_1);
    IB(1, 1);
  }
  int kt = 0;
  while (true) {
    BODY(0, 1, 1, 0);
    ++kt; if (kt >= nk) break;
    BODY(1, 0, 0, 1);
    ++kt; if (kt >= nk) break;
  }
#undef IB
#undef IA
#undef EW
#undef COMP
#undef BODY

  const int row0 = bm * 64 + ((lane >> 4) << 2);
  const int col0 = bn * 256 + wn + l15;
#pragma unroll
  for (int i = 0; i < 4; ++i)
#pragma unroll
    for (int j = 0; j < 4; ++j) {
      int col = col0 + j * 16;
#pragma unroll
      for (int r = 0; r < 4; ++r)
        ob[(size_t)(row0 + i * 16 + r) * 1024 + col] = acc[i][j][r];
    }
}

// ---------------- host ----------------
extern "C" void kernel_launch(void* const* d_in, const int* in_sizes, int n_in,
                              void* d_out, int out_size, void* d_ws, size_t ws_size,
                              hipStream_t stream) {
  const float* x  = (const float*)d_in[0];
  const float* Wq = (const float*)d_in[1];
  const float* Wk = (const float*)d_in[2];
  const float* Wv = (const float*)d_in[3];
  float* out = (float*)d_out;
  char* ws = (char*)d_ws;

  ushort* Qh = (ushort*)(ws);                 // 16,777,216
  ushort* Kh = (ushort*)(ws + 16777216);      // 16,777,216
  ushort* Vt = (ushort*)(ws + 33554432);      // 16,777,216
  float*  Sc = (float*) (ws + 50331648);      // 4 x 2048*2048*4 = 67,108,864
  // transient (dead before Sc is written):
  ushort* xh = (ushort*)(ws + 50331648);      // dead after QKV
  ushort* Wt = (ushort*)(ws + 67108864);      // dead after QKV
  ushort* Vh = (ushort*)(ws + 73400320);      // dead after tr_v
  // stats at tail:
  float*  pm = (float*) (ws + 117440512);     // 524,288
  float*  pz = (float*) (ws + 117964800);     // 524,288
  float*  cm = (float*) (ws + 118489088);     // 32,768
  float*  cz = (float*) (ws + 118521856);     // 32,768  (end ~118.6 MB)

  k_cvt_xw<<<11264, 256, 0, stream>>>(x, xh, Wq, Wk, Wv, Wt);
  k_gemm32<0><<<1536, 256, 0, stream>>>(xh, Wt, Qh, Kh, Vh, nullptr, nullptr);
  k_tr_v<<<dim3(16, 32, 4), 256, 0, stream>>>(Vh, Vt);
  k_gemm32<1><<<dim3(16, 16, 4), 256, 0, stream>>>(Qh, Kh, Sc, nullptr, nullptr, pm, pz);
  k_stats2<<<dim3(8, 1, 4), 256, 0, stream>>>(pm, pz, cm, cz);
  k_pv<<<512, 256, 0, stream>>>(Sc, cm, cz, Vt, out);
}

// Round 10
// 182.198 us; speedup vs baseline: 1.2361x; 1.2361x over previous
//
#include <hip/hip_runtime.h>
#include <stdint.h>

// B=4, S=2048, d=1024. fp32 in/out, f16 MFMA internally.
// cvt(x,W) -> QKV gemm (128^2, BK=32, triple-buffer, counted vmcnt(4),
// conflict-free swizzle) -> [scores gemm (compact triangular grid, fused
// col-stats) + V-transpose tail blocks in ONE dispatch] -> stats2 ->
// PV (64x256, round-8 paired-bm mapping, dbuf + split staging).

typedef __attribute__((ext_vector_type(8))) _Float16 half8;
typedef __attribute__((ext_vector_type(4))) float f32x4;
typedef __attribute__((ext_vector_type(8))) unsigned short ushort8;

__device__ __forceinline__ ushort f2h(float f) {
  _Float16 h = (_Float16)f;
  union { _Float16 h; ushort u; } v; v.h = h; return v.u;
}

__device__ __forceinline__ void gload_lds16(const ushort* g, ushort* l) {
  __builtin_amdgcn_global_load_lds(
      (const __attribute__((address_space(1))) void*)g,
      (__attribute__((address_space(3))) void*)l, 16, 0, 0);
}

// ------------- merged convert kernel: x f32->f16, W f32->f16 transposed ------
__global__ void k_cvt_xw(const float* __restrict__ x, ushort* __restrict__ xh,
                         const float* __restrict__ Wq, const float* __restrict__ Wk,
                         const float* __restrict__ Wv, ushort* __restrict__ Wt) {
  __shared__ ushort tile[32][33];
  int bid = blockIdx.x;
  if (bid < 8192) {
    int i = (bid * 256 + threadIdx.x) * 4;
    float4 v = *(const float4*)(x + i);
    ushort4 o;
    o.x = f2h(v.x); o.y = f2h(v.y); o.z = f2h(v.z); o.w = f2h(v.w);
    *(ushort4*)(xh + i) = o;
  } else {
    int wb = bid - 8192;                 // 0..3071
    int zz = wb >> 10;                   // matrix id
    int rem = wb & 1023;
    int e0 = (rem & 31) * 32, d0 = (rem >> 5) * 32;
    const float* W = zz == 0 ? Wq : zz == 1 ? Wk : Wv;
    int tix = threadIdx.x & 31, tiy = threadIdx.x >> 5;
    for (int r = tiy; r < 32; r += 8)
      tile[r][tix] = f2h(W[(size_t)(d0 + r) * 1024 + e0 + tix]);
    __syncthreads();
    ushort* out = Wt + (size_t)zz * 1024 * 1024;
    for (int r = tiy; r < 32; r += 8)
      out[(size_t)(e0 + r) * 1024 + d0 + tix] = tile[tix][r];
  }
}

// ======= QKV: 128x128 GEMM engine, BK=32, triple-buffer, vmcnt(4) =======
// Swizzle: phys_chunk = chunk ^ ((row>>1)&3) (0-conflict, round-7 proven).
__global__ __launch_bounds__(256)
void k_qkv(const ushort* __restrict__ A, const ushort* __restrict__ Bt,
           ushort* __restrict__ Qo, ushort* __restrict__ Ko,
           ushort* __restrict__ Vo) {
  int wg = blockIdx.x;                        // 1536 = 8 * 192, bijective
  int swz = (wg & 7) * 192 + (wg >> 3);
  int bm = swz / 24, bn = swz % 24;

  __shared__ __align__(16) ushort As[3][128 * 32];
  __shared__ __align__(16) ushort Bs[3][128 * 32];

  const int t = threadIdx.x, lane = t & 63, wv = t >> 6;
  const int wm = (wv >> 1) * 64, wn = (wv & 1) * 64, l15 = lane & 15;
  const int srcc = (((t & 3) ^ ((t >> 3) & 3)) * 8);
  const ushort* ga = A + (size_t)(bm * 128 + (t >> 2)) * 1024 + srcc;
  const ushort* gb = Bt + (size_t)(bn * 128 + (t >> 2)) * 1024 + srcc;
  const int dst0 = t * 8;

  int rA[4], rB[4];
#pragma unroll
  for (int i = 0; i < 4; ++i) {
    rA[i] = (wm + i * 16 + l15) * 32;
    rB[i] = (wn + i * 16 + l15) * 32;
  }
  const int ck = (((lane >> 4) ^ ((l15 >> 1) & 3)) << 3);

  f32x4 acc[4][4] = {};

#define STG(kt)                                                              \
  {                                                                          \
    ushort* la = (ushort*)As[(kt) % 3] + dst0;                               \
    ushort* lb = (ushort*)Bs[(kt) % 3] + dst0;                               \
    gload_lds16(ga + (kt) * 32, la);                                         \
    gload_lds16(ga + 65536 + (kt) * 32, la + 2048);                          \
    gload_lds16(gb + (kt) * 32, lb);                                         \
    gload_lds16(gb + 65536 + (kt) * 32, lb + 2048);                          \
  }
  STG(0);
  STG(1);
  for (int kt = 0; kt < 32; ++kt) {
    if (kt < 31) asm volatile("s_waitcnt vmcnt(4)" ::: "memory");
    else         asm volatile("s_waitcnt vmcnt(0)" ::: "memory");
    __builtin_amdgcn_s_barrier();
    __builtin_amdgcn_sched_barrier(0);
    if (kt + 2 < 32) STG(kt + 2);
    const ushort* Ab = As[kt % 3];
    const ushort* Bb = Bs[kt % 3];
    half8 af[4], bf[4];
#pragma unroll
    for (int i = 0; i < 4; ++i) {
      af[i] = *(const half8*)&Ab[rA[i] + ck];
      bf[i] = *(const half8*)&Bb[rB[i] + ck];
    }
    __builtin_amdgcn_s_setprio(1);
#pragma unroll
    for (int i = 0; i < 4; ++i)
#pragma unroll
      for (int j = 0; j < 4; ++j)
        acc[i][j] = __builtin_amdgcn_mfma_f32_16x16x32_f16(af[i], bf[j], acc[i][j], 0, 0, 0);
    __builtin_amdgcn_s_setprio(0);
  }
#undef STG

  const int row0 = bm * 128 + wm + ((lane >> 4) << 2);
  const int colb = bn * 128 + wn + l15;
  int mat = bn >> 3;
  ushort* dst = mat == 0 ? Qo : mat == 1 ? Ko : Vo;
  int cn0 = colb & 1023;
#pragma unroll
  for (int i = 0; i < 4; ++i)
#pragma unroll
    for (int j = 0; j < 4; ++j)
#pragma unroll
      for (int r = 0; r < 4; ++r)
        dst[(size_t)(row0 + i * 16 + r) * 1024 + cn0 + j * 16] = f2h(acc[i][j][r]);
}

// ==== scores (compact triangular grid, fused col-stats) + V-transpose tail ===
// wg < 544: scores block (idx = wg>>2 triangular, z = wg&3).
// wg >= 544: V-transpose 64x64 tile (2048 blocks).
__global__ __launch_bounds__(256)
void k_scores_tr(const ushort* __restrict__ Qh, const ushort* __restrict__ Kh,
                 float* __restrict__ Sc, float* __restrict__ pm,
                 float* __restrict__ pz, const ushort* __restrict__ V,
                 ushort* __restrict__ Vt) {
  __shared__ __align__(16) ushort As[3][128 * 32];
  __shared__ __align__(16) ushort Bs[3][128 * 32];
  __shared__ float red[4][4][16][2];

  const int t = threadIdx.x;
  int wg = blockIdx.x;

  if (wg >= 544) {
    // ---- V transpose tail: Vh [b][j][e] -> Vt [b][e][j], 64x64 tiles ----
    int ti = wg - 544;
    int b = ti >> 9, rem = ti & 511;
    int e0 = (rem & 15) * 64, j0 = (rem >> 4) * 64;
    ushort(*tile)[72] = (ushort(*)[72]) & As[0][0];  // 9.2 KB of the 24 KB
    const ushort* src = V + (size_t)b * 2097152;
    ushort* dst = Vt + (size_t)b * 2097152;
    int r = t >> 3, c = (t & 7) * 8;
#pragma unroll
    for (int h = 0; h < 2; ++h) {
      ushort8 v8 = *(const ushort8*)&src[(size_t)(j0 + h * 32 + r) * 1024 + e0 + c];
      *(ushort8*)&tile[h * 32 + r][c] = v8;
    }
    __syncthreads();
#pragma unroll
    for (int h = 0; h < 2; ++h) {
      int er = h * 32 + r;
      ushort8 o;
#pragma unroll
      for (int q = 0; q < 8; ++q) o[q] = tile[c + q][er];
      *(ushort8*)&dst[(size_t)(e0 + er) * 2048 + j0 + c] = o;
    }
    return;
  }

  // ---- scores block: compact triangular decode ----
  const int idx = wg >> 2, bz = wg & 3;
  int bm = (int)((sqrtf(8.0f * (float)idx + 1.0f) - 1.0f) * 0.5f);
  while ((bm + 1) * (bm + 2) / 2 <= idx) ++bm;
  while (bm * (bm + 1) / 2 > idx) --bm;
  const int bn = idx - bm * (bm + 1) / 2;      // bn <= bm

  const ushort* A = Qh + (size_t)bz * 2097152;
  const ushort* Bt = Kh + (size_t)bz * 2097152;

  const int lane = t & 63, wv = t >> 6;
  const int wm = (wv >> 1) * 64, wn = (wv & 1) * 64, l15 = lane & 15;
  const int srcc = (((t & 3) ^ ((t >> 3) & 3)) * 8);
  const ushort* ga = A + (size_t)(bm * 128 + (t >> 2)) * 1024 + srcc;
  const ushort* gb = Bt + (size_t)(bn * 128 + (t >> 2)) * 1024 + srcc;
  const int dst0 = t * 8;

  int rA[4], rB[4];
#pragma unroll
  for (int i = 0; i < 4; ++i) {
    rA[i] = (wm + i * 16 + l15) * 32;
    rB[i] = (wn + i * 16 + l15) * 32;
  }
  const int ck = (((lane >> 4) ^ ((l15 >> 1) & 3)) << 3);

  f32x4 acc[4][4] = {};

#define STG(kt)                                                              \
  {                                                                          \
    ushort* la = (ushort*)As[(kt) % 3] + dst0;                               \
    ushort* lb = (ushort*)Bs[(kt) % 3] + dst0;                               \
    gload_lds16(ga + (kt) * 32, la);                                         \
    gload_lds16(ga + 65536 + (kt) * 32, la + 2048);                          \
    gload_lds16(gb + (kt) * 32, lb);                                         \
    gload_lds16(gb + 65536 + (kt) * 32, lb + 2048);                         \
  }
  STG(0);
  STG(1);
  for (int kt = 0; kt < 32; ++kt) {
    if (kt < 31) asm volatile("s_waitcnt vmcnt(4)" ::: "memory");
    else         asm volatile("s_waitcnt vmcnt(0)" ::: "memory");
    __builtin_amdgcn_s_barrier();
    __builtin_amdgcn_sched_barrier(0);
    if (kt + 2 < 32) STG(kt + 2);
    const ushort* Ab = As[kt % 3];
    const ushort* Bb = Bs[kt % 3];
    half8 af[4], bf[4];
#pragma unroll
    for (int i = 0; i < 4; ++i) {
      af[i] = *(const half8*)&Ab[rA[i] + ck];
      bf[i] = *(const half8*)&Bb[rB[i] + ck];
    }
    __builtin_amdgcn_s_setprio(1);
#pragma unroll
    for (int i = 0; i < 4; ++i)
#pragma unroll
      for (int j = 0; j < 4; ++j)
        acc[i][j] = __builtin_amdgcn_mfma_f32_16x16x32_f16(af[i], bf[j], acc[i][j], 0, 0, 0);
    __builtin_amdgcn_s_setprio(0);
  }
#undef STG

  const int row0 = bm * 128 + wm + ((lane >> 4) << 2);
  const int colb = bn * 128 + wn + l15;
  float* sc = Sc + (size_t)bz * 4194304;
  float fm[4] = {-1e30f, -1e30f, -1e30f, -1e30f};
  float fz[4] = {0.f, 0.f, 0.f, 0.f};
#pragma unroll
  for (int i = 0; i < 4; ++i)
#pragma unroll
    for (int j = 0; j < 4; ++j) {
      int col = colb + j * 16;
#pragma unroll
      for (int r = 0; r < 4; ++r) {
        int row = row0 + i * 16 + r;
        bool ok = col <= row;
        float w = ok ? acc[i][j][r] * 0.03125f : -1e30f;  // 1/sqrt(1024)
        sc[(size_t)row * 2048 + col] = w;
        float nm = fmaxf(fm[j], w);
        fz[j] = fz[j] * __expf(fm[j] - nm) + (ok ? __expf(w - nm) : 0.f);
        fm[j] = nm;
      }
    }
#pragma unroll
  for (int j = 0; j < 4; ++j) {
#pragma unroll
    for (int mk = 16; mk <= 32; mk <<= 1) {
      float om = __shfl_xor(fm[j], mk);
      float oz = __shfl_xor(fz[j], mk);
      float nm = fmaxf(fm[j], om);
      fz[j] = fz[j] * __expf(fm[j] - nm) + oz * __expf(om - nm);
      fm[j] = nm;
    }
  }
  if (lane < 16) {
#pragma unroll
    for (int j = 0; j < 4; ++j) {
      red[wv][j][l15][0] = fm[j];
      red[wv][j][l15][1] = fz[j];
    }
  }
  __syncthreads();
  if (t < 128) {
    int wnid = t >> 6, jj = (t >> 4) & 3, ll = t & 15;
    float m0 = red[wnid][jj][ll][0], z0 = red[wnid][jj][ll][1];
    float m1 = red[wnid + 2][jj][ll][0], z1 = red[wnid + 2][jj][ll][1];
    float nm = fmaxf(m0, m1);
    float zz = z0 * __expf(m0 - nm) + z1 * __expf(m1 - nm);
    size_t po = ((size_t)bz * 16 + bm) * 2048 + bn * 128 + wnid * 64 + jj * 16 + ll;
    pm[po] = nm;
    pz[po] = zz;
  }
}

// ---- stats2: combine 16 row-tile partials per column (skip unwritten) ----
__global__ void k_stats2(const float* __restrict__ pm, const float* __restrict__ pz,
                         float* __restrict__ cm, float* __restrict__ cz) {
  int b = blockIdx.z;
  int j = blockIdx.x * 256 + threadIdx.x;
  int cmin = j >> 7;
  float m = -1e30f;
  for (int c = cmin; c < 16; ++c)
    m = fmaxf(m, pm[((size_t)b * 16 + c) * 2048 + j]);
  float zs = 0.f;
  for (int c = cmin; c < 16; ++c) {
    float zz = pz[((size_t)b * 16 + c) * 2048 + j];
    if (zz > 0.f) zs += zz * __expf(pm[((size_t)b * 16 + c) * 2048 + j] - m);
  }
  cm[(size_t)b * 2048 + j] = m;
  cz[(size_t)b * 2048 + j] = zs > 0.f ? 1.0f / zs : 0.f;
}

// ===== PV gemm: 64x256 tiles, 512 blocks (ROUND-8 paired-bm mapping), dbuf ====
__global__ __launch_bounds__(256, 2)
void k_pv(const float* __restrict__ Sc, const float* __restrict__ cm,
          const float* __restrict__ cz, const ushort* __restrict__ Vt,
          float* __restrict__ out) {
  const int wg = blockIdx.x;
  const int half = wg >> 8, q = wg & 255;
  const int bn = q & 3, bmi = (q >> 2) & 31;
  const int z = (q >> 7) + 2 * half;
  const int bm = half ? 31 - bmi : bmi;   // CU pairing: bm + bm' = 31
  const float* S = Sc + (size_t)z * 4194304;
  const float* cmb = cm + (size_t)z * 2048;
  const float* czb = cz + (size_t)z * 2048;
  const ushort* Vb = Vt + (size_t)z * 2097152;
  float* ob = out + (size_t)z * 2097152;

  __shared__ __align__(16) ushort As[2][64 * 64];    // 16 KB
  __shared__ __align__(16) ushort Bs[2][256 * 64];   // 64 KB

  const int t = threadIdx.x, lane = t & 63, wv = t >> 6;
  const int wn = wv * 64, l15 = lane & 15;
  const int nk = bm + 1;

  const int tr = t >> 3;                       // 0..31
  const int lc = (t & 7) ^ (tr & 7);           // logical 16B chunk (swizzle inv)
  const ushort* gB = Vb + (size_t)(bn * 256 + tr) * 2048 + lc * 8;
  const float*  gS = S + (size_t)(bm * 64 + tr) * 2048 + lc * 8;

  f32x4 acc[4][4] = {};
  f32x4 a0_0, a1_0, a2_0, a3_0, m0_0, m1_0, z0_0, z1_0;
  f32x4 a0_1, a1_1, a2_1, a3_1, m0_1, m1_1, z0_1, z1_1;

#define IB(kt, buf)                                                           \
  {                                                                           \
    ushort* lb = (ushort*)Bs[buf] + t * 8;                                    \
    const ushort* src = gB + (kt) * 64;                                       \
    _Pragma("unroll") for (int g2 = 0; g2 < 8; ++g2)                          \
        gload_lds16(src + (size_t)(g2 * 32) * 2048, lb + g2 * 2048);          \
  }
#define IA(kt, A0, A1, A2, A3, M0, M1, Z0, Z1)                                \
  {                                                                           \
    const float* sp = gS + (kt) * 64;                                         \
    A0 = *(const f32x4*)sp;                                                   \
    A1 = *(const f32x4*)(sp + 4);                                             \
    A2 = *(const f32x4*)(sp + 32 * 2048);                                     \
    A3 = *(const f32x4*)(sp + 32 * 2048 + 4);                                 \
    const float* mp = cmb + (kt) * 64 + lc * 8;                               \
    const float* zp = czb + (kt) * 64 + lc * 8;                               \
    M0 = *(const f32x4*)mp; M1 = *(const f32x4*)(mp + 4);                     \
    Z0 = *(const f32x4*)zp; Z1 = *(const f32x4*)(zp + 4);                     \
  }
#define EW(buf, A0, A1, A2, A3, M0, M1, Z0, Z1)                               \
  {                                                                           \
    ushort8 p;                                                                \
    _Pragma("unroll") for (int qq = 0; qq < 4; ++qq) {                        \
      p[qq] = f2h(__expf(A0[qq] - M0[qq]) * Z0[qq]);                          \
      p[4 + qq] = f2h(__expf(A1[qq] - M1[qq]) * Z1[qq]);                      \
    }                                                                         \
    *(ushort8*)&As[buf][t * 8] = p;                                           \
    _Pragma("unroll") for (int qq = 0; qq < 4; ++qq) {                        \
      p[qq] = f2h(__expf(A2[qq] - M0[qq]) * Z0[qq]);                          \
      p[4 + qq] = f2h(__expf(A3[qq] - M1[qq]) * Z1[qq]);                      \
    }                                                                         \
    *(ushort8*)&As[buf][t * 8 + 2048] = p;                                    \
  }
#define COMP(buf)                                                             \
  {                                                                           \
    _Pragma("unroll") for (int kk = 0; kk < 2; ++kk) {                        \
      const int cpk = (((kk * 4) + (lane >> 4)) ^ (l15 & 7)) * 8;             \
      half8 af[4], bf[4];                                                     \
      _Pragma("unroll") for (int i = 0; i < 4; ++i) {                         \
        af[i] = *(const half8*)&As[buf][(i * 16 + l15) * 64 + cpk];           \
        bf[i] = *(const half8*)&Bs[buf][(wn + i * 16 + l15) * 64 + cpk];      \
      }                                                                       \
      __builtin_amdgcn_s_setprio(1);                                          \
      _Pragma("unroll") for (int i = 0; i < 4; ++i)                           \
          _Pragma("unroll") for (int j = 0; j < 4; ++j)                       \
          acc[i][j] = __builtin_amdgcn_mfma_f32_16x16x32_f16(                 \
              af[i], bf[j], acc[i][j], 0, 0, 0);                              \
      __builtin_amdgcn_s_setprio(0);                                         \
    }                                                                         \
  }
#define BODY(buf, nbuf, S2, S3)                                               \
  {                                                                           \
    if (kt + 1 < nk) asm volatile("s_waitcnt vmcnt(16)" ::: "memory");        \
    else             asm volatile("s_waitcnt vmcnt(0)" ::: "memory");         \
    __builtin_amdgcn_s_barrier();                                             \
    __builtin_amdgcn_sched_barrier(0);                                        \
    COMP(buf);                                                                \
    if (kt + 1 < nk) {                                                        \
      EW(nbuf, a0_##S2, a1_##S2, a2_##S2, a3_##S2, m0_##S2, m1_##S2,          \
         z0_##S2, z1_##S2);                                                   \
    }                                                                         \
    asm volatile("s_waitcnt lgkmcnt(0)" ::: "memory");                        \
    __builtin_amdgcn_s_barrier();                                             \
    __builtin_amdgcn_sched_barrier(0);                                        \
    if (kt + 2 < nk) {                                                        \
      IA(kt + 2, a0_##S3, a1_##S3, a2_##S3, a3_##S3, m0_##S3, m1_##S3,        \
         z0_##S3, z1_##S3);                                                   \
      IB(kt + 2, buf);                                                        \
    }                                                                         \
  }

  IA(0, a0_0, a1_0, a2_0, a3_0, m0_0, m1_0, z0_0, z1_0);
  IB(0, 0);
  EW(0, a0_0, a1_0, a2_0, a3_0, m0_0, m1_0, z0_0, z1_0);
  if (nk > 1) {
    IA(1, a0_1, a1_1, a2_1, a3_1, m0_1, m1_1, z0_1, z1_1);
    IB(1, 1);
  }
  int kt = 0;
  while (true) {
    BODY(0, 1, 1, 0);
    ++kt; if (kt >= nk) break;
    BODY(1, 0, 0, 1);
    ++kt; if (kt >= nk) break;
  }
#undef IB
#undef IA
#undef EW
#undef COMP
#undef BODY

  const int row0 = bm * 64 + ((lane >> 4) << 2);
  const int col0 = bn * 256 + wn + l15;
#pragma unroll
  for (int i = 0; i < 4; ++i)
#pragma unroll
    for (int j = 0; j < 4; ++j) {
      int col = col0 + j * 16;
#pragma unroll
      for (int r = 0; r < 4; ++r)
        ob[(size_t)(row0 + i * 16 + r) * 1024 + col] = acc[i][j][r];
    }
}

// ---------------- host ----------------
extern "C" void kernel_launch(void* const* d_in, const int* in_sizes, int n_in,
                              void* d_out, int out_size, void* d_ws, size_t ws_size,
                              hipStream_t stream) {
  const float* x  = (const float*)d_in[0];
  const float* Wq = (const float*)d_in[1];
  const float* Wk = (const float*)d_in[2];
  const float* Wv = (const float*)d_in[3];
  float* out = (float*)d_out;
  char* ws = (char*)d_ws;

  ushort* Qh = (ushort*)(ws);                 // 16,777,216
  ushort* Kh = (ushort*)(ws + 16777216);      // 16,777,216
  ushort* Vt = (ushort*)(ws + 33554432);      // 16,777,216
  float*  Sc = (float*) (ws + 50331648);      // 4 x 2048*2048*4 = 67,108,864
  // transient (dead before Sc is written):
  ushort* xh = (ushort*)(ws + 50331648);      // dead after QKV
  ushort* Wt = (ushort*)(ws + 67108864);      // dead after QKV
  ushort* Vh = (ushort*)(ws + 73400320);      // dead after scores_tr
  // stats at tail:
  float*  pm = (float*) (ws + 117440512);     // 524,288
  float*  pz = (float*) (ws + 117964800);     // 524,288
  float*  cm = (float*) (ws + 118489088);     // 32,768
  float*  cz = (float*) (ws + 118521856);     // 32,768  (end ~118.6 MB)

  k_cvt_xw<<<11264, 256, 0, stream>>>(x, xh, Wq, Wk, Wv, Wt);
  k_qkv<<<1536, 256, 0, stream>>>(xh, Wt, Qh, Kh, Vh);
  // scores (544 compact triangular blocks) + V-transpose (2048 tail blocks)
  k_scores_tr<<<2592, 256, 0, stream>>>(Qh, Kh, Sc, pm, pz, Vh, Vt);
  k_stats2<<<dim3(8, 1, 4), 256, 0, stream>>>(pm, pz, cm, cz);
  k_pv<<<512, 256, 0, stream>>>(Sc, cm, cz, Vt, out);
}

// Round 11
// 170.790 us; speedup vs baseline: 1.3187x; 1.0668x over previous
//
#include <hip/hip_runtime.h>
#include <stdint.h>

// B=4, S=2048, d=1024. fp32 in/out, f16 MFMA internally.
// cvt(x,W) -> QKV gemm (128^2 BK=32 triple-buffer engine; V blocks write Vt
// TRANSPOSED directly) -> scores gemm (544 compact triangular blocks, fused
// col-stats) -> stats2 -> PV (64x256, paired-bm, dbuf, 3-deep Sc prefetch).

typedef __attribute__((ext_vector_type(8))) _Float16 half8;
typedef __attribute__((ext_vector_type(4))) float f32x4;
typedef __attribute__((ext_vector_type(8))) unsigned short ushort8;

__device__ __forceinline__ ushort f2h(float f) {
  _Float16 h = (_Float16)f;
  union { _Float16 h; ushort u; } v; v.h = h; return v.u;
}

__device__ __forceinline__ void gload_lds16(const ushort* g, ushort* l) {
  __builtin_amdgcn_global_load_lds(
      (const __attribute__((address_space(1))) void*)g,
      (__attribute__((address_space(3))) void*)l, 16, 0, 0);
}

// ------------- merged convert kernel: x f32->f16, W f32->f16 transposed ------
__global__ void k_cvt_xw(const float* __restrict__ x, ushort* __restrict__ xh,
                         const float* __restrict__ Wq, const float* __restrict__ Wk,
                         const float* __restrict__ Wv, ushort* __restrict__ Wt) {
  __shared__ ushort tile[32][33];
  int bid = blockIdx.x;
  if (bid < 8192) {
    int i = (bid * 256 + threadIdx.x) * 4;
    float4 v = *(const float4*)(x + i);
    ushort4 o;
    o.x = f2h(v.x); o.y = f2h(v.y); o.z = f2h(v.z); o.w = f2h(v.w);
    *(ushort4*)(xh + i) = o;
  } else {
    int wb = bid - 8192;                 // 0..3071
    int zz = wb >> 10;                   // matrix id
    int rem = wb & 1023;
    int e0 = (rem & 31) * 32, d0 = (rem >> 5) * 32;
    const float* W = zz == 0 ? Wq : zz == 1 ? Wk : Wv;
    int tix = threadIdx.x & 31, tiy = threadIdx.x >> 5;
    for (int r = tiy; r < 32; r += 8)
      tile[r][tix] = f2h(W[(size_t)(d0 + r) * 1024 + e0 + tix]);
    __syncthreads();
    ushort* out = Wt + (size_t)zz * 1024 * 1024;
    for (int r = tiy; r < 32; r += 8)
      out[(size_t)(e0 + r) * 1024 + d0 + tix] = tile[tix][r];
  }
}

// ======= QKV: 128x128 GEMM engine, BK=32, triple-buffer, vmcnt(4) =======
// Swizzle: phys_chunk = chunk ^ ((row>>1)&3) (0-conflict).
// bn<16 -> Q/K row-major; bn>=16 -> V written TRANSPOSED to Vt[b][e][s].
__global__ __launch_bounds__(256)
void k_qkv(const ushort* __restrict__ A, const ushort* __restrict__ Bt,
           ushort* __restrict__ Qo, ushort* __restrict__ Ko,
           ushort* __restrict__ Vt) {
  int wg = blockIdx.x;                        // 1536 = 8 * 192, bijective
  int swz = (wg & 7) * 192 + (wg >> 3);
  int bm = swz / 24, bn = swz % 24;

  __shared__ __align__(16) ushort As[3][128 * 32];
  __shared__ __align__(16) ushort Bs[3][128 * 32];

  const int t = threadIdx.x, lane = t & 63, wv = t >> 6;
  const int wm = (wv >> 1) * 64, wn = (wv & 1) * 64, l15 = lane & 15;
  const int srcc = (((t & 3) ^ ((t >> 3) & 3)) * 8);
  const ushort* ga = A + (size_t)(bm * 128 + (t >> 2)) * 1024 + srcc;
  const ushort* gb = Bt + (size_t)(bn * 128 + (t >> 2)) * 1024 + srcc;
  const int dst0 = t * 8;

  int rA[4], rB[4];
#pragma unroll
  for (int i = 0; i < 4; ++i) {
    rA[i] = (wm + i * 16 + l15) * 32;
    rB[i] = (wn + i * 16 + l15) * 32;
  }
  const int ck = (((lane >> 4) ^ ((l15 >> 1) & 3)) << 3);

  f32x4 acc[4][4] = {};

#define STG(kt)                                                              \
  {                                                                          \
    ushort* la = (ushort*)As[(kt) % 3] + dst0;                               \
    ushort* lb = (ushort*)Bs[(kt) % 3] + dst0;                               \
    gload_lds16(ga + (kt) * 32, la);                                         \
    gload_lds16(ga + 65536 + (kt) * 32, la + 2048);                          \
    gload_lds16(gb + (kt) * 32, lb);                                         \
    gload_lds16(gb + 65536 + (kt) * 32, lb + 2048);                          \
  }
  STG(0);
  STG(1);
  for (int kt = 0; kt < 32; ++kt) {
    if (kt < 31) asm volatile("s_waitcnt vmcnt(4)" ::: "memory");
    else         asm volatile("s_waitcnt vmcnt(0)" ::: "memory");
    __builtin_amdgcn_s_barrier();
    __builtin_amdgcn_sched_barrier(0);
    if (kt + 2 < 32) STG(kt + 2);
    const ushort* Ab = As[kt % 3];
    const ushort* Bb = Bs[kt % 3];
    half8 af[4], bf[4];
#pragma unroll
    for (int i = 0; i < 4; ++i) {
      af[i] = *(const half8*)&Ab[rA[i] + ck];
      bf[i] = *(const half8*)&Bb[rB[i] + ck];
    }
    __builtin_amdgcn_s_setprio(1);
#pragma unroll
    for (int i = 0; i < 4; ++i)
#pragma unroll
      for (int j = 0; j < 4; ++j)
        acc[i][j] = __builtin_amdgcn_mfma_f32_16x16x32_f16(af[i], bf[j], acc[i][j], 0, 0, 0);
    __builtin_amdgcn_s_setprio(0);
  }
#undef STG

  const int row0 = bm * 128 + wm + ((lane >> 4) << 2);
  const int colb = bn * 128 + wn + l15;
  if (bn < 16) {
    // Q or K, row-major
    ushort* dst = (bn >> 3) == 0 ? Qo : Ko;
    int cn0 = colb & 1023;
#pragma unroll
    for (int i = 0; i < 4; ++i)
#pragma unroll
      for (int j = 0; j < 4; ++j)
#pragma unroll
        for (int r = 0; r < 4; ++r)
          dst[(size_t)(row0 + i * 16 + r) * 1024 + cn0 + j * 16] = f2h(acc[i][j][r]);
  } else {
    // V: write transposed into Vt[b][e][s]; 128-row tiles never straddle batches
    int b = bm >> 4;
    ushort* vt = Vt + (size_t)b * 2097152;
    int s0 = row0 & 2047;
    int cn0 = colb & 1023;
#pragma unroll
    for (int i = 0; i < 4; ++i)
#pragma unroll
      for (int j = 0; j < 4; ++j) {
        int e = cn0 + j * 16;
        ushort4 p;
        p.x = f2h(acc[i][j][0]); p.y = f2h(acc[i][j][1]);
        p.z = f2h(acc[i][j][2]); p.w = f2h(acc[i][j][3]);
        *(ushort4*)&vt[(size_t)e * 2048 + s0 + i * 16] = p;
      }
  }
}

// ==== scores: 544 compact triangular blocks, fused column (m,z) partials ====
__global__ __launch_bounds__(256)
void k_scores(const ushort* __restrict__ Qh, const ushort* __restrict__ Kh,
              float* __restrict__ Sc, float* __restrict__ pm,
              float* __restrict__ pz) {
  __shared__ __align__(16) ushort As[3][128 * 32];
  __shared__ __align__(16) ushort Bs[3][128 * 32];
  __shared__ float red[4][4][16][2];

  const int t = threadIdx.x;
  const int wg = blockIdx.x;
  const int idx = wg >> 2, bz = wg & 3;
  int bm = (int)((sqrtf(8.0f * (float)idx + 1.0f) - 1.0f) * 0.5f);
  while ((bm + 1) * (bm + 2) / 2 <= idx) ++bm;
  while (bm * (bm + 1) / 2 > idx) --bm;
  const int bn = idx - bm * (bm + 1) / 2;      // bn <= bm

  const ushort* A = Qh + (size_t)bz * 2097152;
  const ushort* Bt = Kh + (size_t)bz * 2097152;

  const int lane = t & 63, wv = t >> 6;
  const int wm = (wv >> 1) * 64, wn = (wv & 1) * 64, l15 = lane & 15;
  const int srcc = (((t & 3) ^ ((t >> 3) & 3)) * 8);
  const ushort* ga = A + (size_t)(bm * 128 + (t >> 2)) * 1024 + srcc;
  const ushort* gb = Bt + (size_t)(bn * 128 + (t >> 2)) * 1024 + srcc;
  const int dst0 = t * 8;

  int rA[4], rB[4];
#pragma unroll
  for (int i = 0; i < 4; ++i) {
    rA[i] = (wm + i * 16 + l15) * 32;
    rB[i] = (wn + i * 16 + l15) * 32;
  }
  const int ck = (((lane >> 4) ^ ((l15 >> 1) & 3)) << 3);

  f32x4 acc[4][4] = {};

#define STG(kt)                                                              \
  {                                                                          \
    ushort* la = (ushort*)As[(kt) % 3] + dst0;                               \
    ushort* lb = (ushort*)Bs[(kt) % 3] + dst0;                               \
    gload_lds16(ga + (kt) * 32, la);                                         \
    gload_lds16(ga + 65536 + (kt) * 32, la + 2048);                          \
    gload_lds16(gb + (kt) * 32, lb);                                         \
    gload_lds16(gb + 65536 + (kt) * 32, lb + 2048);                          \
  }
  STG(0);
  STG(1);
  for (int kt = 0; kt < 32; ++kt) {
    if (kt < 31) asm volatile("s_waitcnt vmcnt(4)" ::: "memory");
    else         asm volatile("s_waitcnt vmcnt(0)" ::: "memory");
    __builtin_amdgcn_s_barrier();
    __builtin_amdgcn_sched_barrier(0);
    if (kt + 2 < 32) STG(kt + 2);
    const ushort* Ab = As[kt % 3];
    const ushort* Bb = Bs[kt % 3];
    half8 af[4], bf[4];
#pragma unroll
    for (int i = 0; i < 4; ++i) {
      af[i] = *(const half8*)&Ab[rA[i] + ck];
      bf[i] = *(const half8*)&Bb[rB[i] + ck];
    }
    __builtin_amdgcn_s_setprio(1);
#pragma unroll
    for (int i = 0; i < 4; ++i)
#pragma unroll
      for (int j = 0; j < 4; ++j)
        acc[i][j] = __builtin_amdgcn_mfma_f32_16x16x32_f16(af[i], bf[j], acc[i][j], 0, 0, 0);
    __builtin_amdgcn_s_setprio(0);
  }
#undef STG

  const int row0 = bm * 128 + wm + ((lane >> 4) << 2);
  const int colb = bn * 128 + wn + l15;
  float* sc = Sc + (size_t)bz * 4194304;
  float fm[4] = {-1e30f, -1e30f, -1e30f, -1e30f};
  float fz[4] = {0.f, 0.f, 0.f, 0.f};
#pragma unroll
  for (int i = 0; i < 4; ++i)
#pragma unroll
    for (int j = 0; j < 4; ++j) {
      int col = colb + j * 16;
#pragma unroll
      for (int r = 0; r < 4; ++r) {
        int row = row0 + i * 16 + r;
        bool ok = col <= row;
        float w = ok ? acc[i][j][r] * 0.03125f : -1e30f;  // 1/sqrt(1024)
        sc[(size_t)row * 2048 + col] = w;
        float nm = fmaxf(fm[j], w);
        fz[j] = fz[j] * __expf(fm[j] - nm) + (ok ? __expf(w - nm) : 0.f);
        fm[j] = nm;
      }
    }
#pragma unroll
  for (int j = 0; j < 4; ++j) {
#pragma unroll
    for (int mk = 16; mk <= 32; mk <<= 1) {
      float om = __shfl_xor(fm[j], mk);
      float oz = __shfl_xor(fz[j], mk);
      float nm = fmaxf(fm[j], om);
      fz[j] = fz[j] * __expf(fm[j] - nm) + oz * __expf(om - nm);
      fm[j] = nm;
    }
  }
  if (lane < 16) {
#pragma unroll
    for (int j = 0; j < 4; ++j) {
      red[wv][j][l15][0] = fm[j];
      red[wv][j][l15][1] = fz[j];
    }
  }
  __syncthreads();
  if (t < 128) {
    int wnid = t >> 6, jj = (t >> 4) & 3, ll = t & 15;
    float m0 = red[wnid][jj][ll][0], z0 = red[wnid][jj][ll][1];
    float m1 = red[wnid + 2][jj][ll][0], z1 = red[wnid + 2][jj][ll][1];
    float nm = fmaxf(m0, m1);
    float zz = z0 * __expf(m0 - nm) + z1 * __expf(m1 - nm);
    size_t po = ((size_t)bz * 16 + bm) * 2048 + bn * 128 + wnid * 64 + jj * 16 + ll;
    pm[po] = nm;
    pz[po] = zz;
  }
}

// ---- stats2: combine 16 row-tile partials per column (skip unwritten) ----
__global__ void k_stats2(const float* __restrict__ pm, const float* __restrict__ pz,
                         float* __restrict__ cm, float* __restrict__ cz) {
  int b = blockIdx.z;
  int j = blockIdx.x * 256 + threadIdx.x;
  int cmin = j >> 7;
  float m = -1e30f;
  for (int c = cmin; c < 16; ++c)
    m = fmaxf(m, pm[((size_t)b * 16 + c) * 2048 + j]);
  float zs = 0.f;
  for (int c = cmin; c < 16; ++c) {
    float zz = pz[((size_t)b * 16 + c) * 2048 + j];
    if (zz > 0.f) zs += zz * __expf(pm[((size_t)b * 16 + c) * 2048 + j] - m);
  }
  cm[(size_t)b * 2048 + j] = m;
  cz[(size_t)b * 2048 + j] = zs > 0.f ? 1.0f / zs : 0.f;
}

// ===== PV gemm: 64x256 tiles, 512 blocks (paired-bm), dbuf LDS, 3-deep Sc
// register prefetch (EW at kt consumes IA issued at kt-2: ~2 phases > HBM lat)
__global__ __launch_bounds__(256, 2)
void k_pv(const float* __restrict__ Sc, const float* __restrict__ cm,
          const float* __restrict__ cz, const ushort* __restrict__ Vt,
          float* __restrict__ out) {
  const int wg = blockIdx.x;
  const int half = wg >> 8, q = wg & 255;
  const int bn = q & 3, bmi = (q >> 2) & 31;
  const int z = (q >> 7) + 2 * half;
  const int bm = half ? 31 - bmi : bmi;   // CU pairing: bm + bm' = 31
  const float* S = Sc + (size_t)z * 4194304;
  const float* cmb = cm + (size_t)z * 2048;
  const float* czb = cz + (size_t)z * 2048;
  const ushort* Vb = Vt + (size_t)z * 2097152;
  float* ob = out + (size_t)z * 2097152;

  __shared__ __align__(16) ushort As[2][64 * 64];    // 16 KB
  __shared__ __align__(16) ushort Bs[2][256 * 64];   // 64 KB

  const int t = threadIdx.x, lane = t & 63, wv = t >> 6;
  const int wn = wv * 64, l15 = lane & 15;
  const int nk = bm + 1;

  const int tr = t >> 3;                       // 0..31
  const int lc = (t & 7) ^ (tr & 7);           // logical 16B chunk (swizzle inv)
  const ushort* gB = Vb + (size_t)(bn * 256 + tr) * 2048 + lc * 8;
  const float*  gS = S + (size_t)(bm * 64 + tr) * 2048 + lc * 8;

  f32x4 acc[4][4] = {};
  // three named Sc-staging register sets (static indexing only, rule 20)
  f32x4 a0_0, a1_0, a2_0, a3_0, m0_0, m1_0, z0_0, z1_0;
  f32x4 a0_1, a1_1, a2_1, a3_1, m0_1, m1_1, z0_1, z1_1;
  f32x4 a0_2, a1_2, a2_2, a3_2, m0_2, m1_2, z0_2, z1_2;

#define IB(kt, buf)                                                           \
  {                                                                           \
    ushort* lb = (ushort*)Bs[buf] + t * 8;                                    \
    const ushort* src = gB + (kt) * 64;                                       \
    _Pragma("unroll") for (int g2 = 0; g2 < 8; ++g2)                          \
        gload_lds16(src + (size_t)(g2 * 32) * 2048, lb + g2 * 2048);          \
  }
#define IA(kt, SS)                                                            \
  {                                                                           \
    const float* sp = gS + (kt) * 64;                                         \
    a0_##SS = *(const f32x4*)sp;                                              \
    a1_##SS = *(const f32x4*)(sp + 4);                                        \
    a2_##SS = *(const f32x4*)(sp + 32 * 2048);                                \
    a3_##SS = *(const f32x4*)(sp + 32 * 2048 + 4);                            \
    const float* mp = cmb + (kt) * 64 + lc * 8;                               \
    const float* zp = czb + (kt) * 64 + lc * 8;                               \
    m0_##SS = *(const f32x4*)mp; m1_##SS = *(const f32x4*)(mp + 4);           \
    z0_##SS = *(const f32x4*)zp; z1_##SS = *(const f32x4*)(zp + 4);           \
  }
#define EW(buf, SS)                                                           \
  {                                                                           \
    ushort8 p;                                                                \
    _Pragma("unroll") for (int qq = 0; qq < 4; ++qq) {                        \
      p[qq] = f2h(__expf(a0_##SS[qq] - m0_##SS[qq]) * z0_##SS[qq]);           \
      p[4 + qq] = f2h(__expf(a1_##SS[qq] - m1_##SS[qq]) * z1_##SS[qq]);       \
    }                                                                         \
    *(ushort8*)&As[buf][t * 8] = p;                                           \
    _Pragma("unroll") for (int qq = 0; qq < 4; ++qq) {                        \
      p[qq] = f2h(__expf(a2_##SS[qq] - m0_##SS[qq]) * z0_##SS[qq]);           \
      p[4 + qq] = f2h(__expf(a3_##SS[qq] - m1_##SS[qq]) * z1_##SS[qq]);       \
    }                                                                         \
    *(ushort8*)&As[buf][t * 8 + 2048] = p;                                    \
  }
#define COMP(buf)                                                             \
  {                                                                           \
    _Pragma("unroll") for (int kk = 0; kk < 2; ++kk) {                        \
      const int cpk = (((kk * 4) + (lane >> 4)) ^ (l15 & 7)) * 8;             \
      half8 af[4], bf[4];                                                     \
      _Pragma("unroll") for (int i = 0; i < 4; ++i) {                         \
        af[i] = *(const half8*)&As[buf][(i * 16 + l15) * 64 + cpk];           \
        bf[i] = *(const half8*)&Bs[buf][(wn + i * 16 + l15) * 64 + cpk];      \
      }                                                                       \
      __builtin_amdgcn_s_setprio(1);                                          \
      _Pragma("unroll") for (int i = 0; i < 4; ++i)                           \
          _Pragma("unroll") for (int j = 0; j < 4; ++j)                       \
          acc[i][j] = __builtin_amdgcn_mfma_f32_16x16x32_f16(                 \
              af[i], bf[j], acc[i][j], 0, 0, 0);                              \
      __builtin_amdgcn_s_setprio(0);                                         \
    }                                                                         \
  }
// body at kt: buf = kt&1; EW target As[buf^1] from set (kt+1)%3;
// prefetch IA(kt+3) into set (kt+3)%3 == kt%3; IB(kt+2) into Bs[kt&1].
#define BODY(buf, SN, SP)                                                     \
  {                                                                           \
    if (kt + 1 < nk) asm volatile("s_waitcnt vmcnt(16)" ::: "memory");        \
    else             asm volatile("s_waitcnt vmcnt(0)" ::: "memory");         \
    __builtin_amdgcn_s_barrier();                                             \
    __builtin_amdgcn_sched_barrier(0);                                        \
    COMP(buf);                                                                \
    if (kt + 1 < nk) { EW(buf ^ 1, SN); }                                     \
    asm volatile("s_waitcnt lgkmcnt(0)" ::: "memory");                        \
    __builtin_amdgcn_s_barrier();                                             \
    __builtin_amdgcn_sched_barrier(0);                                        \
    if (kt + 3 < nk) { IA(kt + 3, SP); }                                      \
    if (kt + 2 < nk) { IB(kt + 2, buf); }                                     \
  }

  // prologue: 3-deep IA, 2-deep IB, As[0] filled from set 0
  IA(0, 0);
  IB(0, 0);
  EW(0, 0);
  if (nk > 1) { IA(1, 1); IB(1, 1); }
  if (nk > 2) { IA(2, 2); }
  int kt = 0;
  while (true) {
    BODY(0, 1, 0); ++kt; if (kt >= nk) break;   // kt%6==0
    BODY(1, 2, 1); ++kt; if (kt >= nk) break;   // 1
    BODY(0, 0, 2); ++kt; if (kt >= nk) break;   // 2
    BODY(1, 1, 0); ++kt; if (kt >= nk) break;   // 3
    BODY(0, 2, 1); ++kt; if (kt >= nk) break;   // 4
    BODY(1, 0, 2); ++kt; if (kt >= nk) break;   // 5
  }
#undef IB
#undef IA
#undef EW
#undef COMP
#undef BODY

  const int row0 = bm * 64 + ((lane >> 4) << 2);
  const int col0 = bn * 256 + wn + l15;
#pragma unroll
  for (int i = 0; i < 4; ++i)
#pragma unroll
    for (int j = 0; j < 4; ++j) {
      int col = col0 + j * 16;
#pragma unroll
      for (int r = 0; r < 4; ++r)
        ob[(size_t)(row0 + i * 16 + r) * 1024 + col] = acc[i][j][r];
    }
}

// ---------------- host ----------------
extern "C" void kernel_launch(void* const* d_in, const int* in_sizes, int n_in,
                              void* d_out, int out_size, void* d_ws, size_t ws_size,
                              hipStream_t stream) {
  const float* x  = (const float*)d_in[0];
  const float* Wq = (const float*)d_in[1];
  const float* Wk = (const float*)d_in[2];
  const float* Wv = (const float*)d_in[3];
  float* out = (float*)d_out;
  char* ws = (char*)d_ws;

  ushort* Qh = (ushort*)(ws);                 // 16,777,216
  ushort* Kh = (ushort*)(ws + 16777216);      // 16,777,216
  ushort* Vt = (ushort*)(ws + 33554432);      // 16,777,216
  float*  Sc = (float*) (ws + 50331648);      // 4 x 2048*2048*4 = 67,108,864
  // transient (dead before Sc is written):
  ushort* xh = (ushort*)(ws + 50331648);      // dead after QKV
  ushort* Wt = (ushort*)(ws + 67108864);      // dead after QKV
  // stats at tail:
  float*  pm = (float*) (ws + 117440512);     // 524,288
  float*  pz = (float*) (ws + 117964800);     // 524,288
  float*  cm = (float*) (ws + 118489088);     // 32,768
  float*  cz = (float*) (ws + 118521856);     // 32,768  (end ~118.6 MB)

  k_cvt_xw<<<11264, 256, 0, stream>>>(x, xh, Wq, Wk, Wv, Wt);
  k_qkv<<<1536, 256, 0, stream>>>(xh, Wt, Qh, Kh, Vt);   // V -> Vt directly
  k_scores<<<544, 256, 0, stream>>>(Qh, Kh, Sc, pm, pz);
  k_stats2<<<dim3(8, 1, 4), 256, 0, stream>>>(pm, pz, cm, cz);
  k_pv<<<512, 256, 0, stream>>>(Sc, cm, cz, Vt, out);
}